// Round 11
// baseline (1271.718 us; speedup 1.0000x reference)
//
#include <hip/hip_runtime.h>
#include <math.h>

#define NT 256

__device__ __forceinline__ float rlf(float v, int l) {
    return __int_as_float(__builtin_amdgcn_readlane(__float_as_int(v), l));
}
__device__ __forceinline__ int imin(int a, int b) { return a < b ? a : b; }
__device__ __forceinline__ int imax(int a, int b) { return a > b ? a : b; }

// ---------------- CSR build ----------------

__global__ void zero_i32(int* __restrict__ p, int n) {
    int t = blockIdx.x * blockDim.x + threadIdx.x;
    if (t < n) p[t] = 0;
}

__global__ void hist_dst(int* __restrict__ cnt, const int* __restrict__ dst, int n_edges) {
    int e = blockIdx.x * blockDim.x + threadIdx.x;
    if (e < n_edges) atomicAdd(&cnt[dst[e]], 1);
}

// single-block exclusive scan of cnt[0..n) -> row_off[0..n], cursor[0..n)
__global__ void scan_offsets(const int* __restrict__ cnt, int* __restrict__ row_off,
                             int* __restrict__ cursor, int n) {
    __shared__ int tsum[1024];
    int tid = threadIdx.x;
    int chunk = (n + 1023) / 1024;
    int beg = tid * chunk;
    int end = beg + chunk; if (end > n) end = n;
    int s = 0;
    for (int i = beg; i < end; ++i) s += cnt[i];
    tsum[tid] = s;
    __syncthreads();
    for (int off = 1; off < 1024; off <<= 1) {
        int v = (tid >= off) ? tsum[tid - off] : 0;
        __syncthreads();
        tsum[tid] += v;
        __syncthreads();
    }
    int run = (tid == 0) ? 0 : tsum[tid - 1];
    for (int i = beg; i < end; ++i) {
        row_off[i] = run;
        cursor[i] = run;
        run += cnt[i];
    }
    if (tid == 1023) row_off[n] = tsum[1023];
}

__global__ void edge_scatter(int* __restrict__ csr_src, int* __restrict__ cursor,
                             const int* __restrict__ src, const int* __restrict__ dst,
                             int n_edges) {
    int e = blockIdx.x * blockDim.x + threadIdx.x;
    if (e < n_edges) {
        int p = atomicAdd(&cursor[dst[e]], 1);
        csr_src[p] = src[e];
    }
}

// transpose weights into [k4][f][kk] layout: out[k4*256 + f*4 + kk] = W[f*64 + k4*4 + kk]
__global__ void wtrans(float* __restrict__ out, const float* __restrict__ W) {
    int t = blockIdx.x * blockDim.x + threadIdx.x;
    if (t < 4096) {
        int kk = t & 3, f = (t >> 2) & 63, k4 = t >> 8;
        out[t] = W[f * 64 + k4 * 4 + kk];
    }
}

// ---------------- pooling helpers ----------------

__global__ void pool_init(float* __restrict__ pooled, int n) {
    int t = blockIdx.x * blockDim.x + threadIdx.x;
    if (t < n) pooled[t] = -INFINITY;
}

__device__ __forceinline__ void atomicMaxFloat(float* addr, float value) {
    if (value >= 0.0f)
        atomicMax((int*)addr, __float_as_int(value));
    else
        atomicMin((unsigned int*)addr, (unsigned int)__float_as_int(value));
}

// ---------------- fused SAGE layer (slot-parallel float4 gather) ----------------
// Wave = 4 edge-slots x 16 feature-lanes; each lane owns a float4 feature
// quarter. One global_load_dwordx4 fetches 4 edges' worth of one quarter ->
// a deg<=32 node is 8 independent idx loads + 8 independent dwordx4 loads,
// branch-free, masked adds (no padding traffic). Cross-slot butterfly via
// shfl_xor(16,32). Dense: WL in LDS (ds_read_b128, conflict-free), WrT from
// global (L1-hot), broadcasts via readlane of (component, lane k4).
__global__ __launch_bounds__(NT, 6) void sage_layer(
    float* __restrict__ out, float* __restrict__ pooled,
    const float* __restrict__ h_in,
    const int* __restrict__ row_off, const int* __restrict__ csr_src,
    const int* __restrict__ batch,
    const float* __restrict__ Wl, const float* __restrict__ WrT,
    const float* __restrict__ bl,
    int n_nodes, int do_pool) {
    __shared__ float WL[4096];  // WL[k4*256 + f*4 + kk] = Wl[f][k4*4+kk]
    int tid = threadIdx.x;
    for (int t = tid; t < 4096; t += NT) {
        int kk = t & 3, f = (t >> 2) & 63, k4 = t >> 8;
        WL[t] = Wl[f * 64 + k4 * 4 + kk];
    }
    __syncthreads();

    int lane = tid & 63;
    int slot = lane >> 4;        // 0..3 edge slot
    int fq   = (lane & 15) * 4;  // feature quarter base
    int gwave = (blockIdx.x * NT + tid) >> 6;
    int nwaves = (gridDim.x * NT) >> 6;
    float bias = bl[lane];

    for (int i = gwave; i < n_nodes; i += nwaves) {
        int beg = row_off[i];
        int end_ = row_off[i + 1];
        int deg = end_ - beg;
        int last = imax(end_ - 1, 0);

        float4 hv4 = *(const float4*)&h_in[(size_t)i * 64 + fq];

        float ax = 0.f, ay = 0.f, az = 0.f, aw = 0.f;
        if (deg <= 32) {
            // ---- fast path: 8 independent idx loads + 8 independent data loads ----
            int sb = beg + slot;
            int l0 = imin(sb + 0,  last);
            int l1 = imin(sb + 4,  last);
            int l2 = imin(sb + 8,  last);
            int l3 = imin(sb + 12, last);
            int l4 = imin(sb + 16, last);
            int l5 = imin(sb + 20, last);
            int l6 = imin(sb + 24, last);
            int l7 = imin(sb + 28, last);
            int idx0 = csr_src[l0];
            int idx1 = csr_src[l1];
            int idx2 = csr_src[l2];
            int idx3 = csr_src[l3];
            int idx4 = csr_src[l4];
            int idx5 = csr_src[l5];
            int idx6 = csr_src[l6];
            int idx7 = csr_src[l7];
            float4 v0 = *(const float4*)&h_in[(size_t)idx0 * 64 + fq];
            float4 v1 = *(const float4*)&h_in[(size_t)idx1 * 64 + fq];
            float4 v2 = *(const float4*)&h_in[(size_t)idx2 * 64 + fq];
            float4 v3 = *(const float4*)&h_in[(size_t)idx3 * 64 + fq];
            float4 v4 = *(const float4*)&h_in[(size_t)idx4 * 64 + fq];
            float4 v5 = *(const float4*)&h_in[(size_t)idx5 * 64 + fq];
            float4 v6 = *(const float4*)&h_in[(size_t)idx6 * 64 + fq];
            float4 v7 = *(const float4*)&h_in[(size_t)idx7 * 64 + fq];
#define ACC4(V, J)                                                            \
            {                                                                 \
                bool ok = (4 * (J) + slot) < deg;                             \
                ax += ok ? V.x : 0.f;                                         \
                ay += ok ? V.y : 0.f;                                         \
                az += ok ? V.z : 0.f;                                         \
                aw += ok ? V.w : 0.f;                                         \
            }
            ACC4(v0, 0) ACC4(v1, 1) ACC4(v2, 2) ACC4(v3, 3)
            ACC4(v4, 4) ACC4(v5, 5) ACC4(v6, 6) ACC4(v7, 7)
#undef ACC4
        } else {
            // ---- slow path (deg > 32): looped 4-edge blocks, same layout ----
            for (int cb = beg; cb < end_; cb += 4) {
                int lidx = imin(cb + slot, last);
                int idx = csr_src[lidx];
                float4 v = *(const float4*)&h_in[(size_t)idx * 64 + fq];
                bool ok = (cb + slot) < end_;
                ax += ok ? v.x : 0.f;
                ay += ok ? v.y : 0.f;
                az += ok ? v.z : 0.f;
                aw += ok ? v.w : 0.f;
            }
        }
        // ---- cross-slot butterfly (slot pairs 16 apart, then 32 apart) ----
        ax += __shfl_xor(ax, 16); ay += __shfl_xor(ay, 16);
        az += __shfl_xor(az, 16); aw += __shfl_xor(aw, 16);
        ax += __shfl_xor(ax, 32); ay += __shfl_xor(ay, 32);
        az += __shfl_xor(az, 32); aw += __shfl_xor(aw, 32);

        float inv = 1.0f / (float)imax(deg, 1);
        float mx = ax * inv, my = ay * inv, mz = az * inv, mw = aw * inv;

        // ---- dense: o[f=lane] = sum_k m[k]*Wl[k][f] + hv[k]*Wr[k][f] + b ----
        float o = bias;
#pragma unroll
        for (int k4 = 0; k4 < 16; ++k4) {
            float4 wl = *(const float4*)&WL[k4 * 256 + lane * 4];
            float4 wr = *(const float4*)&WrT[k4 * 256 + lane * 4];
            o += rlf(mx, k4) * wl.x + rlf(hv4.x, k4) * wr.x;
            o += rlf(my, k4) * wl.y + rlf(hv4.y, k4) * wr.y;
            o += rlf(mz, k4) * wl.z + rlf(hv4.z, k4) * wr.z;
            o += rlf(mw, k4) * wl.w + rlf(hv4.w, k4) * wr.w;
        }
        o = tanhf(o);

        if (do_pool) {
            atomicMaxFloat(&pooled[(size_t)batch[i] * 64 + lane], o);
        } else {
            out[(size_t)i * 64 + lane] = o;
        }
    }
}

// ---------------- MLP head ----------------
__global__ void head(float* __restrict__ out, const float* __restrict__ pooled,
                     const float* __restrict__ W1, const float* __restrict__ b1,
                     const float* __restrict__ W2, const float* __restrict__ b2) {
    __shared__ float W1T[64][64];
    int tid = threadIdx.x;
    for (int t = tid; t < 4096; t += NT) {
        int f = t >> 6, k = t & 63;
        W1T[k][f] = W1[t];
    }
    __syncthreads();

    int lane = tid & 63;
    int g = blockIdx.x * (NT >> 6) + (tid >> 6);
    float v = pooled[(size_t)g * 64 + lane];
    float bias = b1[lane];
#pragma unroll
    for (int it = 0; it < 3; ++it) {
        float acc = bias;
#pragma unroll
        for (int k = 0; k < 64; ++k) {
            acc += rlf(v, k) * W1T[k][lane];
        }
        v = tanhf(acc);
    }
#pragma unroll
    for (int j = 0; j < 3; ++j) {
        float p = v * W2[j * 64 + lane];
#pragma unroll
        for (int off = 32; off >= 1; off >>= 1) p += __shfl_xor(p, off);
        if (lane == 0) out[g * 3 + j] = p + b2[j];
    }
}

// ---------------- launch ----------------

extern "C" void kernel_launch(void* const* d_in, const int* in_sizes, int n_in,
                              void* d_out, int out_size, void* d_ws, size_t ws_size,
                              hipStream_t stream) {
    const float* x   = (const float*)d_in[0];
    const float* Wl0 = (const float*)d_in[1];
    const float* Wr0 = (const float*)d_in[2];
    const float* bl0 = (const float*)d_in[3];
    const float* Wl  = (const float*)d_in[4];
    const float* Wr  = (const float*)d_in[5];
    const float* bl  = (const float*)d_in[6];
    const float* W1  = (const float*)d_in[7];
    const float* b1  = (const float*)d_in[8];
    const float* W2  = (const float*)d_in[9];
    const float* b2  = (const float*)d_in[10];
    const int* ei    = (const int*)d_in[11];
    const int* batch = (const int*)d_in[12];

    int n_nodes = in_sizes[0] / 64;
    int n_edges = in_sizes[11] / 2;
    const int* src = ei;
    const int* dst = ei + n_edges;

    float* bufA   = (float*)d_ws;                         // n_nodes*64
    float* bufB   = bufA + (size_t)n_nodes * 64;          // n_nodes*64
    int* csr_src  = (int*)(bufB + (size_t)n_nodes * 64);  // n_edges
    int* row_off  = csr_src + n_edges;                    // n_nodes+1
    int* cursor   = row_off + (n_nodes + 1);              // n_nodes
    int* cnt      = cursor + n_nodes;                     // n_nodes
    float* pooled = (float*)(cnt + n_nodes);              // 128*64
    float* wr0t   = pooled + 128 * 64;                    // 4096
    float* wrt    = wr0t + 4096;                          // 4096

    int eblk = (n_edges + NT - 1) / NT;
    int nblk = (n_nodes + NT - 1) / NT;
    const int pers_blk = 1536;  // 6 blocks/CU x 256 CUs (24 waves/CU)

    // CSR build
    zero_i32<<<nblk, NT, 0, stream>>>(cnt, n_nodes);
    hist_dst<<<eblk, NT, 0, stream>>>(cnt, dst, n_edges);
    scan_offsets<<<1, 1024, 0, stream>>>(cnt, row_off, cursor, n_nodes);
    edge_scatter<<<eblk, NT, 0, stream>>>(csr_src, cursor, src, dst, n_edges);

    // transposed WR copies + pool init
    wtrans<<<16, NT, 0, stream>>>(wr0t, Wr0);
    wtrans<<<16, NT, 0, stream>>>(wrt, Wr);
    pool_init<<<(128 * 64 + NT - 1) / NT, NT, 0, stream>>>(pooled, 128 * 64);

    sage_layer<<<pers_blk, NT, 0, stream>>>(bufA, pooled, x, row_off, csr_src, batch,
                                            Wl0, wr0t, bl0, n_nodes, 0);
    sage_layer<<<pers_blk, NT, 0, stream>>>(bufB, pooled, bufA, row_off, csr_src, batch,
                                            Wl, wrt, bl, n_nodes, 0);
    sage_layer<<<pers_blk, NT, 0, stream>>>(bufA, pooled, bufB, row_off, csr_src, batch,
                                            Wl, wrt, bl, n_nodes, 0);
    sage_layer<<<pers_blk, NT, 0, stream>>>(bufB, pooled, bufA, row_off, csr_src, batch,
                                            Wl, wrt, bl, n_nodes, 1);

    head<<<32, NT, 0, stream>>>((float*)d_out, pooled, W1, b1, W2, b2);
}

// Round 12
// 559.590 us; speedup vs baseline: 2.2726x; 2.2726x over previous
//
#include <hip/hip_runtime.h>
#include <math.h>

#define NT 256    // small kernels
#define NTS 512   // sage_layer: 8 waves, WL+WR in 32KB LDS, 4 blocks/CU

__device__ __forceinline__ float rlf(float v, int l) {
    return __int_as_float(__builtin_amdgcn_readlane(__float_as_int(v), l));
}
__device__ __forceinline__ int rli(int v, int l) {
    return __builtin_amdgcn_readlane(v, l);
}
__device__ __forceinline__ int imin(int a, int b) { return a < b ? a : b; }
__device__ __forceinline__ int imax(int a, int b) { return a > b ? a : b; }

// ---------------- CSR build ----------------

__global__ void zero_i32(int* __restrict__ p, int n) {
    int t = blockIdx.x * blockDim.x + threadIdx.x;
    if (t < n) p[t] = 0;
}

__global__ void hist_dst(int* __restrict__ cnt, const int* __restrict__ dst, int n_edges) {
    int e = blockIdx.x * blockDim.x + threadIdx.x;
    if (e < n_edges) atomicAdd(&cnt[dst[e]], 1);
}

// single-block exclusive scan of cnt[0..n) -> row_off[0..n], cursor[0..n)
__global__ void scan_offsets(const int* __restrict__ cnt, int* __restrict__ row_off,
                             int* __restrict__ cursor, int n) {
    __shared__ int tsum[1024];
    int tid = threadIdx.x;
    int chunk = (n + 1023) / 1024;
    int beg = tid * chunk;
    int end = beg + chunk; if (end > n) end = n;
    int s = 0;
    for (int i = beg; i < end; ++i) s += cnt[i];
    tsum[tid] = s;
    __syncthreads();
    for (int off = 1; off < 1024; off <<= 1) {
        int v = (tid >= off) ? tsum[tid - off] : 0;
        __syncthreads();
        tsum[tid] += v;
        __syncthreads();
    }
    int run = (tid == 0) ? 0 : tsum[tid - 1];
    for (int i = beg; i < end; ++i) {
        row_off[i] = run;
        cursor[i] = run;
        run += cnt[i];
    }
    if (tid == 1023) row_off[n] = tsum[1023];
}

__global__ void edge_scatter(int* __restrict__ csr_src, int* __restrict__ cursor,
                             const int* __restrict__ src, const int* __restrict__ dst,
                             int n_edges) {
    int e = blockIdx.x * blockDim.x + threadIdx.x;
    if (e < n_edges) {
        int p = atomicAdd(&cursor[dst[e]], 1);
        csr_src[p] = src[e];
    }
}

// ---------------- pooling helpers ----------------

__global__ void pool_init(float* __restrict__ pooled, int n) {
    int t = blockIdx.x * blockDim.x + threadIdx.x;
    if (t < n) pooled[t] = -INFINITY;
}

__device__ __forceinline__ void atomicMaxFloat(float* addr, float value) {
    if (value >= 0.0f)
        atomicMax((int*)addr, __float_as_int(value));
    else
        atomicMin((unsigned int*)addr, (unsigned int)__float_as_int(value));
}

// ---------------- fused SAGE layer ----------------
// r4/r10-proven gather pattern (wave=node-row, lane=feature, 8-deep readlane
// broadcast, one coalesced 256B row per edge). This round: 512-thread blocks
// with BOTH weight matrices in LDS (32KB) -> 4 blocks/CU = 32 waves/CU and
// zero dense-phase VMEM; per-quad idx/hv loads hoisted (8 independent loads
// in flight before first consume); 32-bit element offsets in the gather.
__global__ __launch_bounds__(NTS, 4) void sage_layer(
    float* __restrict__ out, float* __restrict__ pooled,
    const float* __restrict__ h_in,
    const int* __restrict__ row_off, const int* __restrict__ csr_src,
    const int* __restrict__ batch,
    const float* __restrict__ Wl, const float* __restrict__ Wr,
    const float* __restrict__ bl,
    int n_nodes, int do_pool) {
    __shared__ float WL[4096];  // WL[k4*256 + f*4 + kk] = Wl[f][k4*4+kk]
    __shared__ float WR[4096];
    int tid = threadIdx.x;
    for (int t = tid; t < 4096; t += NTS) {
        int kk = t & 3, f = (t >> 2) & 63, k4 = t >> 8;
        WL[t] = Wl[f * 64 + k4 * 4 + kk];
        WR[t] = Wr[f * 64 + k4 * 4 + kk];
    }
    __syncthreads();

    int lane = tid & 63;
    int gwave = (blockIdx.x * NTS + tid) >> 6;
    int nwaves = (gridDim.x * NTS) >> 6;
    float bias = bl[lane];

    for (int q = gwave; q * 4 < n_nodes; q += nwaves) {
        int base = q * 4;
        bool quad_ok = (base + 4 <= n_nodes);

        float mean0 = 0.f, mean1 = 0.f, mean2 = 0.f, mean3 = 0.f;
        float hv0 = 0.f, hv1 = 0.f, hv2 = 0.f, hv3 = 0.f;

        int b0 = 0, b1 = 0, b2 = 0, b3 = 0;
        int d0 = 0, d1 = 0, d2 = 0, d3 = 0, dmax = 0;
        if (quad_ok) {
            int ro = row_off[base + (lane < 4 ? lane : 4)];
            b0 = rli(ro, 0); b1 = rli(ro, 1); b2 = rli(ro, 2); b3 = rli(ro, 3);
            int e3 = rli(ro, 4);
            d0 = b1 - b0; d1 = b2 - b1; d2 = b3 - b2; d3 = e3 - b3;
            dmax = imax(imax(d0, d1), imax(d2, d3));
        }

        if (quad_ok && dmax <= 64) {
            // ---- fast path: hoisted independent loads, r4 inner consume ----
            int idx0 = csr_src[b0 + (lane < d0 ? lane : imax(d0 - 1, 0))];
            int idx1 = csr_src[b1 + (lane < d1 ? lane : imax(d1 - 1, 0))];
            int idx2 = csr_src[b2 + (lane < d2 ? lane : imax(d2 - 1, 0))];
            int idx3 = csr_src[b3 + (lane < d3 ? lane : imax(d3 - 1, 0))];
            hv0 = h_in[((base + 0) << 6) + lane];
            hv1 = h_in[((base + 1) << 6) + lane];
            hv2 = h_in[((base + 2) << 6) + lane];
            hv3 = h_in[((base + 3) << 6) + lane];

#define GATHER_FAST(MEAN, IDX, D)                                             \
            {                                                                 \
                int m = (D);                                                  \
                float a0 = 0.f, a1 = 0.f;                                     \
                for (int j = 0; j < m; j += 8) {                              \
                    int mm1 = m - 1;                                          \
                    int s0 = rli(IDX, j);                                     \
                    int s1 = rli(IDX, j + 1 < m ? j + 1 : mm1);               \
                    int s2 = rli(IDX, j + 2 < m ? j + 2 : mm1);               \
                    int s3 = rli(IDX, j + 3 < m ? j + 3 : mm1);               \
                    int s4 = rli(IDX, j + 4 < m ? j + 4 : mm1);               \
                    int s5 = rli(IDX, j + 5 < m ? j + 5 : mm1);               \
                    int s6 = rli(IDX, j + 6 < m ? j + 6 : mm1);               \
                    int s7 = rli(IDX, j + 7 < m ? j + 7 : mm1);               \
                    float v0 = h_in[(s0 << 6) + lane];                        \
                    float v1 = h_in[(s1 << 6) + lane];                        \
                    float v2 = h_in[(s2 << 6) + lane];                        \
                    float v3 = h_in[(s3 << 6) + lane];                        \
                    float v4 = h_in[(s4 << 6) + lane];                        \
                    float v5 = h_in[(s5 << 6) + lane];                        \
                    float v6 = h_in[(s6 << 6) + lane];                        \
                    float v7 = h_in[(s7 << 6) + lane];                        \
                    a0 += v0;                                                 \
                    a1 += (j + 1 < m) ? v1 : 0.f;                             \
                    a0 += (j + 2 < m) ? v2 : 0.f;                             \
                    a1 += (j + 3 < m) ? v3 : 0.f;                             \
                    a0 += (j + 4 < m) ? v4 : 0.f;                             \
                    a1 += (j + 5 < m) ? v5 : 0.f;                             \
                    a0 += (j + 6 < m) ? v6 : 0.f;                             \
                    a1 += (j + 7 < m) ? v7 : 0.f;                             \
                }                                                             \
                MEAN = (a0 + a1) * (1.0f / (float)imax(m, 1));                \
            }
            GATHER_FAST(mean0, idx0, d0)
            GATHER_FAST(mean1, idx1, d1)
            GATHER_FAST(mean2, idx2, d2)
            GATHER_FAST(mean3, idx3, d3)
#undef GATHER_FAST
        } else {
            // ---- generic slow path (tail quad or deg > 64) ----
#define GATHER_NODE(MEAN, HV, N)                                              \
            {                                                                 \
                int i = base + (N);                                           \
                if (i < n_nodes) {                                            \
                    int beg = row_off[i];                                     \
                    int end_ = row_off[i + 1];                                \
                    int deg = end_ - beg;                                     \
                    float aa = 0.f;                                           \
                    for (int cb = beg; cb < end_; cb += 64) {                 \
                        int m = end_ - cb; if (m > 64) m = 64;                \
                        int lidx = cb + (lane < m ? lane : m - 1);            \
                        int idx = csr_src[lidx];                              \
                        for (int j = 0; j < m; ++j)                           \
                            aa += h_in[(rli(idx, j) << 6) + lane];            \
                    }                                                         \
                    MEAN = aa * (1.0f / (float)(deg > 0 ? deg : 1));          \
                    HV = h_in[((size_t)i << 6) + lane];                       \
                }                                                             \
            }
            GATHER_NODE(mean0, hv0, 0)
            GATHER_NODE(mean1, hv1, 1)
            GATHER_NODE(mean2, hv2, 2)
            GATHER_NODE(mean3, hv3, 3)
#undef GATHER_NODE
        }

        float o0 = bias, o1 = bias, o2 = bias, o3 = bias;
        for (int k4 = 0; k4 < 16; ++k4) {
            float4 wl = *(const float4*)&WL[k4 * 256 + lane * 4];
            float4 wr = *(const float4*)&WR[k4 * 256 + lane * 4];
            int kb = k4 * 4;
#define DENSE_KK(WLK, WRK, KK)                                                \
            {                                                                 \
                int k = kb + (KK);                                            \
                o0 += rlf(mean0, k) * (WLK) + rlf(hv0, k) * (WRK);            \
                o1 += rlf(mean1, k) * (WLK) + rlf(hv1, k) * (WRK);            \
                o2 += rlf(mean2, k) * (WLK) + rlf(hv2, k) * (WRK);            \
                o3 += rlf(mean3, k) * (WLK) + rlf(hv3, k) * (WRK);            \
            }
            DENSE_KK(wl.x, wr.x, 0)
            DENSE_KK(wl.y, wr.y, 1)
            DENSE_KK(wl.z, wr.z, 2)
            DENSE_KK(wl.w, wr.w, 3)
#undef DENSE_KK
        }

        o0 = tanhf(o0); o1 = tanhf(o1); o2 = tanhf(o2); o3 = tanhf(o3);

#define WRITE_NODE(O, N)                                                      \
        {                                                                     \
            int i = base + (N);                                               \
            if (i < n_nodes) {                                                \
                if (do_pool) {                                                \
                    atomicMaxFloat(&pooled[(size_t)batch[i] * 64 + lane], O); \
                } else {                                                      \
                    out[((size_t)i << 6) + lane] = O;                         \
                }                                                             \
            }                                                                 \
        }
        WRITE_NODE(o0, 0)
        WRITE_NODE(o1, 1)
        WRITE_NODE(o2, 2)
        WRITE_NODE(o3, 3)
#undef WRITE_NODE
    }
}

// ---------------- MLP head ----------------
__global__ void head(float* __restrict__ out, const float* __restrict__ pooled,
                     const float* __restrict__ W1, const float* __restrict__ b1,
                     const float* __restrict__ W2, const float* __restrict__ b2) {
    __shared__ float W1T[64][64];
    int tid = threadIdx.x;
    for (int t = tid; t < 4096; t += NT) {
        int f = t >> 6, k = t & 63;
        W1T[k][f] = W1[t];
    }
    __syncthreads();

    int lane = tid & 63;
    int g = blockIdx.x * (NT >> 6) + (tid >> 6);
    float v = pooled[(size_t)g * 64 + lane];
    float bias = b1[lane];
#pragma unroll
    for (int it = 0; it < 3; ++it) {
        float acc = bias;
#pragma unroll
        for (int k = 0; k < 64; ++k) {
            acc += rlf(v, k) * W1T[k][lane];
        }
        v = tanhf(acc);
    }
#pragma unroll
    for (int j = 0; j < 3; ++j) {
        float p = v * W2[j * 64 + lane];
#pragma unroll
        for (int off = 32; off >= 1; off >>= 1) p += __shfl_xor(p, off);
        if (lane == 0) out[g * 3 + j] = p + b2[j];
    }
}

// ---------------- launch ----------------

extern "C" void kernel_launch(void* const* d_in, const int* in_sizes, int n_in,
                              void* d_out, int out_size, void* d_ws, size_t ws_size,
                              hipStream_t stream) {
    const float* x   = (const float*)d_in[0];
    const float* Wl0 = (const float*)d_in[1];
    const float* Wr0 = (const float*)d_in[2];
    const float* bl0 = (const float*)d_in[3];
    const float* Wl  = (const float*)d_in[4];
    const float* Wr  = (const float*)d_in[5];
    const float* bl  = (const float*)d_in[6];
    const float* W1  = (const float*)d_in[7];
    const float* b1  = (const float*)d_in[8];
    const float* W2  = (const float*)d_in[9];
    const float* b2  = (const float*)d_in[10];
    const int* ei    = (const int*)d_in[11];
    const int* batch = (const int*)d_in[12];

    int n_nodes = in_sizes[0] / 64;
    int n_edges = in_sizes[11] / 2;
    const int* src = ei;
    const int* dst = ei + n_edges;

    float* bufA   = (float*)d_ws;                         // n_nodes*64
    float* bufB   = bufA + (size_t)n_nodes * 64;          // n_nodes*64
    int* csr_src  = (int*)(bufB + (size_t)n_nodes * 64);  // n_edges
    int* row_off  = csr_src + n_edges;                    // n_nodes+1
    int* cursor   = row_off + (n_nodes + 1);              // n_nodes
    int* cnt      = cursor + n_nodes;                     // n_nodes
    float* pooled = (float*)(cnt + n_nodes);              // 128*64

    int eblk = (n_edges + NT - 1) / NT;
    int nblk = (n_nodes + NT - 1) / NT;
    const int pers_blk = 1024;  // 4 blocks/CU x 256 CUs = 32 waves/CU

    // CSR build
    zero_i32<<<nblk, NT, 0, stream>>>(cnt, n_nodes);
    hist_dst<<<eblk, NT, 0, stream>>>(cnt, dst, n_edges);
    scan_offsets<<<1, 1024, 0, stream>>>(cnt, row_off, cursor, n_nodes);
    edge_scatter<<<eblk, NT, 0, stream>>>(csr_src, cursor, src, dst, n_edges);

    pool_init<<<(128 * 64 + NT - 1) / NT, NT, 0, stream>>>(pooled, 128 * 64);

    sage_layer<<<pers_blk, NTS, 0, stream>>>(bufA, pooled, x, row_off, csr_src, batch,
                                             Wl0, Wr0, bl0, n_nodes, 0);
    sage_layer<<<pers_blk, NTS, 0, stream>>>(bufB, pooled, bufA, row_off, csr_src, batch,
                                             Wl, Wr, bl, n_nodes, 0);
    sage_layer<<<pers_blk, NTS, 0, stream>>>(bufA, pooled, bufB, row_off, csr_src, batch,
                                             Wl, Wr, bl, n_nodes, 0);
    sage_layer<<<pers_blk, NTS, 0, stream>>>(bufB, pooled, bufA, row_off, csr_src, batch,
                                             Wl, Wr, bl, n_nodes, 1);

    head<<<32, NT, 0, stream>>>((float*)d_out, pooled, W1, b1, W2, b2);
}

// Round 13
// 454.356 us; speedup vs baseline: 2.7989x; 1.2316x over previous
//
#include <hip/hip_runtime.h>
#include <math.h>

#define NT 256    // small kernels
#define NTS 512   // sage_layer: 8 waves, WL+WR in 32KB LDS, 4 blocks/CU

__device__ __forceinline__ float rlf(float v, int l) {
    return __int_as_float(__builtin_amdgcn_readlane(__float_as_int(v), l));
}
__device__ __forceinline__ int rli(int v, int l) {
    return __builtin_amdgcn_readlane(v, l);
}
__device__ __forceinline__ int imin(int a, int b) { return a < b ? a : b; }
__device__ __forceinline__ int imax(int a, int b) { return a > b ? a : b; }

// ---------------- CSR build ----------------

__global__ void zero_i32(int* __restrict__ p, int n) {
    int t = blockIdx.x * blockDim.x + threadIdx.x;
    if (t < n) p[t] = 0;
}

__global__ void hist_dst(int* __restrict__ cnt, const int* __restrict__ dst, int n_edges) {
    int e = blockIdx.x * blockDim.x + threadIdx.x;
    if (e < n_edges) atomicAdd(&cnt[dst[e]], 1);
}

// ---- parallel 3-kernel exclusive scan of cnt[0..n) ----
// 1) per-256-block sums
__global__ void scan_blocks(const int* __restrict__ cnt, int* __restrict__ bsum, int n) {
    __shared__ int s[NT];
    int i = blockIdx.x * NT + threadIdx.x;
    s[threadIdx.x] = (i < n) ? cnt[i] : 0;
    __syncthreads();
    for (int off = NT / 2; off > 0; off >>= 1) {
        if (threadIdx.x < off) s[threadIdx.x] += s[threadIdx.x + off];
        __syncthreads();
    }
    if (threadIdx.x == 0) bsum[blockIdx.x] = s[0];
}

// 2) single-block scan of block sums -> exclusive block offsets + total
__global__ void scan_bsum(const int* __restrict__ bsum, int* __restrict__ boff,
                          int nb, int* __restrict__ row_off, int n) {
    __shared__ int s[1024];
    int tid = threadIdx.x;
    int v = (tid < nb) ? bsum[tid] : 0;
    s[tid] = v;
    __syncthreads();
    for (int off = 1; off < 1024; off <<= 1) {
        int t = (tid >= off) ? s[tid - off] : 0;
        __syncthreads();
        s[tid] += t;
        __syncthreads();
    }
    if (tid < nb) boff[tid] = s[tid] - v;           // exclusive prefix
    if (tid == nb - 1) row_off[n] = s[tid];         // grand total
}

// 3) intra-block scan + block offset -> row_off, cursor
__global__ void scan_final(const int* __restrict__ cnt, const int* __restrict__ boff,
                           int* __restrict__ row_off, int* __restrict__ cursor, int n) {
    __shared__ int s[NT];
    int i = blockIdx.x * NT + threadIdx.x;
    int v = (i < n) ? cnt[i] : 0;
    s[threadIdx.x] = v;
    __syncthreads();
    for (int off = 1; off < NT; off <<= 1) {
        int t = (threadIdx.x >= off) ? s[threadIdx.x - off] : 0;
        __syncthreads();
        s[threadIdx.x] += t;
        __syncthreads();
    }
    if (i < n) {
        int ex = boff[blockIdx.x] + s[threadIdx.x] - v;  // exclusive
        row_off[i] = ex;
        cursor[i] = ex;
    }
}

__global__ void edge_scatter(int* __restrict__ csr_src, int* __restrict__ cursor,
                             const int* __restrict__ src, const int* __restrict__ dst,
                             int n_edges) {
    int e = blockIdx.x * blockDim.x + threadIdx.x;
    if (e < n_edges) {
        int p = atomicAdd(&cursor[dst[e]], 1);
        csr_src[p] = src[e];
    }
}

// ---------------- pooling helpers ----------------

__global__ void pool_init(float* __restrict__ pooled, int n) {
    int t = blockIdx.x * blockDim.x + threadIdx.x;
    if (t < n) pooled[t] = -INFINITY;
}

__device__ __forceinline__ void atomicMaxFloat(float* addr, float value) {
    if (value >= 0.0f)
        atomicMax((int*)addr, __float_as_int(value));
    else
        atomicMin((unsigned int*)addr, (unsigned int)__float_as_int(value));
}

// ---------------- fused SAGE layer (r12-proven) ----------------
__global__ __launch_bounds__(NTS, 4) void sage_layer(
    float* __restrict__ out, float* __restrict__ pooled,
    const float* __restrict__ h_in,
    const int* __restrict__ row_off, const int* __restrict__ csr_src,
    const int* __restrict__ batch,
    const float* __restrict__ Wl, const float* __restrict__ Wr,
    const float* __restrict__ bl,
    int n_nodes, int do_pool) {
    __shared__ float WL[4096];  // WL[k4*256 + f*4 + kk] = Wl[f][k4*4+kk]
    __shared__ float WR[4096];
    int tid = threadIdx.x;
    for (int t = tid; t < 4096; t += NTS) {
        int kk = t & 3, f = (t >> 2) & 63, k4 = t >> 8;
        WL[t] = Wl[f * 64 + k4 * 4 + kk];
        WR[t] = Wr[f * 64 + k4 * 4 + kk];
    }
    __syncthreads();

    int lane = tid & 63;
    int gwave = (blockIdx.x * NTS + tid) >> 6;
    int nwaves = (gridDim.x * NTS) >> 6;
    float bias = bl[lane];

    for (int q = gwave; q * 4 < n_nodes; q += nwaves) {
        int base = q * 4;
        bool quad_ok = (base + 4 <= n_nodes);

        float mean0 = 0.f, mean1 = 0.f, mean2 = 0.f, mean3 = 0.f;
        float hv0 = 0.f, hv1 = 0.f, hv2 = 0.f, hv3 = 0.f;

        int b0 = 0, b1 = 0, b2 = 0, b3 = 0;
        int d0 = 0, d1 = 0, d2 = 0, d3 = 0, dmax = 0;
        if (quad_ok) {
            int ro = row_off[base + (lane < 4 ? lane : 4)];
            b0 = rli(ro, 0); b1 = rli(ro, 1); b2 = rli(ro, 2); b3 = rli(ro, 3);
            int e3 = rli(ro, 4);
            d0 = b1 - b0; d1 = b2 - b1; d2 = b3 - b2; d3 = e3 - b3;
            dmax = imax(imax(d0, d1), imax(d2, d3));
        }

        if (quad_ok && dmax <= 64) {
            // ---- fast path: hoisted independent loads, r4 inner consume ----
            int idx0 = csr_src[b0 + (lane < d0 ? lane : imax(d0 - 1, 0))];
            int idx1 = csr_src[b1 + (lane < d1 ? lane : imax(d1 - 1, 0))];
            int idx2 = csr_src[b2 + (lane < d2 ? lane : imax(d2 - 1, 0))];
            int idx3 = csr_src[b3 + (lane < d3 ? lane : imax(d3 - 1, 0))];
            hv0 = h_in[((base + 0) << 6) + lane];
            hv1 = h_in[((base + 1) << 6) + lane];
            hv2 = h_in[((base + 2) << 6) + lane];
            hv3 = h_in[((base + 3) << 6) + lane];

#define GATHER_FAST(MEAN, IDX, D)                                             \
            {                                                                 \
                int m = (D);                                                  \
                float a0 = 0.f, a1 = 0.f;                                     \
                for (int j = 0; j < m; j += 8) {                              \
                    int mm1 = m - 1;                                          \
                    int s0 = rli(IDX, j);                                     \
                    int s1 = rli(IDX, j + 1 < m ? j + 1 : mm1);               \
                    int s2 = rli(IDX, j + 2 < m ? j + 2 : mm1);               \
                    int s3 = rli(IDX, j + 3 < m ? j + 3 : mm1);               \
                    int s4 = rli(IDX, j + 4 < m ? j + 4 : mm1);               \
                    int s5 = rli(IDX, j + 5 < m ? j + 5 : mm1);               \
                    int s6 = rli(IDX, j + 6 < m ? j + 6 : mm1);               \
                    int s7 = rli(IDX, j + 7 < m ? j + 7 : mm1);               \
                    float v0 = h_in[(s0 << 6) + lane];                        \
                    float v1 = h_in[(s1 << 6) + lane];                        \
                    float v2 = h_in[(s2 << 6) + lane];                        \
                    float v3 = h_in[(s3 << 6) + lane];                        \
                    float v4 = h_in[(s4 << 6) + lane];                        \
                    float v5 = h_in[(s5 << 6) + lane];                        \
                    float v6 = h_in[(s6 << 6) + lane];                        \
                    float v7 = h_in[(s7 << 6) + lane];                        \
                    a0 += v0;                                                 \
                    a1 += (j + 1 < m) ? v1 : 0.f;                             \
                    a0 += (j + 2 < m) ? v2 : 0.f;                             \
                    a1 += (j + 3 < m) ? v3 : 0.f;                             \
                    a0 += (j + 4 < m) ? v4 : 0.f;                             \
                    a1 += (j + 5 < m) ? v5 : 0.f;                             \
                    a0 += (j + 6 < m) ? v6 : 0.f;                             \
                    a1 += (j + 7 < m) ? v7 : 0.f;                             \
                }                                                             \
                MEAN = (a0 + a1) * (1.0f / (float)imax(m, 1));                \
            }
            GATHER_FAST(mean0, idx0, d0)
            GATHER_FAST(mean1, idx1, d1)
            GATHER_FAST(mean2, idx2, d2)
            GATHER_FAST(mean3, idx3, d3)
#undef GATHER_FAST
        } else {
            // ---- generic slow path (tail quad or deg > 64) ----
#define GATHER_NODE(MEAN, HV, N)                                              \
            {                                                                 \
                int i = base + (N);                                           \
                if (i < n_nodes) {                                            \
                    int beg = row_off[i];                                     \
                    int end_ = row_off[i + 1];                                \
                    int deg = end_ - beg;                                     \
                    float aa = 0.f;                                           \
                    for (int cb = beg; cb < end_; cb += 64) {                 \
                        int m = end_ - cb; if (m > 64) m = 64;                \
                        int lidx = cb + (lane < m ? lane : m - 1);            \
                        int idx = csr_src[lidx];                              \
                        for (int j = 0; j < m; ++j)                           \
                            aa += h_in[(rli(idx, j) << 6) + lane];            \
                    }                                                         \
                    MEAN = aa * (1.0f / (float)(deg > 0 ? deg : 1));          \
                    HV = h_in[((size_t)i << 6) + lane];                       \
                }                                                             \
            }
            GATHER_NODE(mean0, hv0, 0)
            GATHER_NODE(mean1, hv1, 1)
            GATHER_NODE(mean2, hv2, 2)
            GATHER_NODE(mean3, hv3, 3)
#undef GATHER_NODE
        }

        float o0 = bias, o1 = bias, o2 = bias, o3 = bias;
        for (int k4 = 0; k4 < 16; ++k4) {
            float4 wl = *(const float4*)&WL[k4 * 256 + lane * 4];
            float4 wr = *(const float4*)&WR[k4 * 256 + lane * 4];
            int kb = k4 * 4;
#define DENSE_KK(WLK, WRK, KK)                                                \
            {                                                                 \
                int k = kb + (KK);                                            \
                o0 += rlf(mean0, k) * (WLK) + rlf(hv0, k) * (WRK);            \
                o1 += rlf(mean1, k) * (WLK) + rlf(hv1, k) * (WRK);            \
                o2 += rlf(mean2, k) * (WLK) + rlf(hv2, k) * (WRK);            \
                o3 += rlf(mean3, k) * (WLK) + rlf(hv3, k) * (WRK);            \
            }
            DENSE_KK(wl.x, wr.x, 0)
            DENSE_KK(wl.y, wr.y, 1)
            DENSE_KK(wl.z, wr.z, 2)
            DENSE_KK(wl.w, wr.w, 3)
#undef DENSE_KK
        }

        o0 = tanhf(o0); o1 = tanhf(o1); o2 = tanhf(o2); o3 = tanhf(o3);

#define WRITE_NODE(O, N)                                                      \
        {                                                                     \
            int i = base + (N);                                               \
            if (i < n_nodes) {                                                \
                if (do_pool) {                                                \
                    atomicMaxFloat(&pooled[(size_t)batch[i] * 64 + lane], O); \
                } else {                                                      \
                    out[((size_t)i << 6) + lane] = O;                         \
                }                                                             \
            }                                                                 \
        }
        WRITE_NODE(o0, 0)
        WRITE_NODE(o1, 1)
        WRITE_NODE(o2, 2)
        WRITE_NODE(o3, 3)
#undef WRITE_NODE
    }
}

// ---------------- MLP head ----------------
__global__ void head(float* __restrict__ out, const float* __restrict__ pooled,
                     const float* __restrict__ W1, const float* __restrict__ b1,
                     const float* __restrict__ W2, const float* __restrict__ b2) {
    __shared__ float W1T[64][64];
    int tid = threadIdx.x;
    for (int t = tid; t < 4096; t += NT) {
        int f = t >> 6, k = t & 63;
        W1T[k][f] = W1[t];
    }
    __syncthreads();

    int lane = tid & 63;
    int g = blockIdx.x * (NT >> 6) + (tid >> 6);
    float v = pooled[(size_t)g * 64 + lane];
    float bias = b1[lane];
#pragma unroll
    for (int it = 0; it < 3; ++it) {
        float acc = bias;
#pragma unroll
        for (int k = 0; k < 64; ++k) {
            acc += rlf(v, k) * W1T[k][lane];
        }
        v = tanhf(acc);
    }
#pragma unroll
    for (int j = 0; j < 3; ++j) {
        float p = v * W2[j * 64 + lane];
#pragma unroll
        for (int off = 32; off >= 1; off >>= 1) p += __shfl_xor(p, off);
        if (lane == 0) out[g * 3 + j] = p + b2[j];
    }
}

// ---------------- launch ----------------

extern "C" void kernel_launch(void* const* d_in, const int* in_sizes, int n_in,
                              void* d_out, int out_size, void* d_ws, size_t ws_size,
                              hipStream_t stream) {
    const float* x   = (const float*)d_in[0];
    const float* Wl0 = (const float*)d_in[1];
    const float* Wr0 = (const float*)d_in[2];
    const float* bl0 = (const float*)d_in[3];
    const float* Wl  = (const float*)d_in[4];
    const float* Wr  = (const float*)d_in[5];
    const float* bl  = (const float*)d_in[6];
    const float* W1  = (const float*)d_in[7];
    const float* b1  = (const float*)d_in[8];
    const float* W2  = (const float*)d_in[9];
    const float* b2  = (const float*)d_in[10];
    const int* ei    = (const int*)d_in[11];
    const int* batch = (const int*)d_in[12];

    int n_nodes = in_sizes[0] / 64;
    int n_edges = in_sizes[11] / 2;
    const int* src = ei;
    const int* dst = ei + n_edges;

    int nb = (n_nodes + NT - 1) / NT;  // scan blocks (196)

    float* bufA   = (float*)d_ws;                         // n_nodes*64
    float* bufB   = bufA + (size_t)n_nodes * 64;          // n_nodes*64
    int* csr_src  = (int*)(bufB + (size_t)n_nodes * 64);  // n_edges
    int* row_off  = csr_src + n_edges;                    // n_nodes+1
    int* cursor   = row_off + (n_nodes + 1);              // n_nodes
    int* cnt      = cursor + n_nodes;                     // n_nodes
    int* bsum     = cnt + n_nodes;                        // nb
    int* boff     = bsum + nb;                            // nb
    float* pooled = (float*)(boff + nb);                  // 128*64

    int eblk = (n_edges + NT - 1) / NT;
    const int pers_blk = 1024;  // 4 blocks/CU x 256 CUs = 32 waves/CU

    // CSR build (parallel scan)
    zero_i32<<<nb, NT, 0, stream>>>(cnt, n_nodes);
    hist_dst<<<eblk, NT, 0, stream>>>(cnt, dst, n_edges);
    scan_blocks<<<nb, NT, 0, stream>>>(cnt, bsum, n_nodes);
    scan_bsum<<<1, 1024, 0, stream>>>(bsum, boff, nb, row_off, n_nodes);
    scan_final<<<nb, NT, 0, stream>>>(cnt, boff, row_off, cursor, n_nodes);
    edge_scatter<<<eblk, NT, 0, stream>>>(csr_src, cursor, src, dst, n_edges);

    pool_init<<<(128 * 64 + NT - 1) / NT, NT, 0, stream>>>(pooled, 128 * 64);

    sage_layer<<<pers_blk, NTS, 0, stream>>>(bufA, pooled, x, row_off, csr_src, batch,
                                             Wl0, Wr0, bl0, n_nodes, 0);
    sage_layer<<<pers_blk, NTS, 0, stream>>>(bufB, pooled, bufA, row_off, csr_src, batch,
                                             Wl, Wr, bl, n_nodes, 0);
    sage_layer<<<pers_blk, NTS, 0, stream>>>(bufA, pooled, bufB, row_off, csr_src, batch,
                                             Wl, Wr, bl, n_nodes, 0);
    sage_layer<<<pers_blk, NTS, 0, stream>>>(bufB, pooled, bufA, row_off, csr_src, batch,
                                             Wl, Wr, bl, n_nodes, 1);

    head<<<32, NT, 0, stream>>>((float*)d_out, pooled, W1, b1, W2, b2);
}